// Round 17
// baseline (304.229 us; speedup 1.0000x reference)
//
#include <hip/hip_runtime.h>

typedef short bf16x8 __attribute__((ext_vector_type(8)));
typedef float f32x4  __attribute__((ext_vector_type(4)));
typedef unsigned short u16;

static __device__ __forceinline__ u16 f2bf(float f) {
    unsigned int u = __builtin_bit_cast(unsigned int, f);
    u += 0x7FFFu + ((u >> 16) & 1u);   // round-to-nearest-even
    return (u16)(u >> 16);
}

static __device__ __forceinline__ void gload_lds16(const void* g, void* l) {
    __builtin_amdgcn_global_load_lds((const __attribute__((address_space(1))) void*)g,
                                     (__attribute__((address_space(3))) void*)l, 16, 0, 0);
}

// ---------------- Kernel 1: demodulate + convert weights to bf16 -------------
// wn[((tap*4 + cc)*128 + co)*32 + ci_in_chunk]  == cc-major [cc108][co128][ci32]
__global__ __launch_bounds__(256) void prep_w_k(const float* __restrict__ w,
                                                u16* __restrict__ wn) {
    const int co = blockIdx.x;
    const int t  = threadIdx.x;
    const float* wc = w + co * 3456;
    float s = 0.f;
    for (int i = t; i < 3456; i += 256) { float v = wc[i]; s += v * v; }
#pragma unroll
    for (int off = 32; off; off >>= 1) s += __shfl_down(s, off);
    __shared__ float red[4];
    __shared__ float dsh;
    if ((t & 63) == 0) red[t >> 6] = s;
    __syncthreads();
    if (t == 0) dsh = rsqrtf(red[0] + red[1] + red[2] + red[3] + 1e-8f);
    __syncthreads();
    const float d = dsh;
    for (int i = t; i < 3456; i += 256) {
        int ci = i / 27, tap = i - ci * 27;
        float v = wc[i] * d;
        wn[((tap * 4 + (ci >> 5)) * 128 + co) * 32 + (ci & 31)] = f2bf(v);
    }
}

// ---------------- Kernel 2: transpose x -> channels-grouped bf16 -------------
// xt[((b*16 + g)*32768 + d*1024 + h*32 + w)*8 + j] = bf16(x[b][g*8+j][d][h][w])
__global__ __launch_bounds__(256) void xpose_k(const float* __restrict__ x,
                                               u16* __restrict__ xt) {
    const int bid = blockIdx.x;
    const int b = bid >> 10, d = (bid >> 5) & 31, h = bid & 31;
    const int t = threadIdx.x;
    const int w = t & 31, cg = t >> 5;
    const int base_dhw = d * 1024 + h * 32 + w;
#pragma unroll
    for (int r = 0; r < 2; ++r) {
        int g = cg + r * 8;
        const float* src = x + ((size_t)(b * 128 + g * 8) << 15) + base_dhw;
        bf16x8 pk;
#pragma unroll
        for (int j = 0; j < 8; ++j) pk[j] = (short)f2bf(src[(size_t)j << 15]);
        *(bf16x8*)&xt[((size_t)((b * 16 + g) << 15) + base_dhw) * 8] = pk;
    }
}

// ---------------- Kernel 3: conv3d — m201-exact 4-phase, BK=64, ring-3 -------
// 512 thr = 8 waves (4 mslice x 2 ncol). Tile M=256 (d2,h4,w32), N=128, BK=64.
// 54 iters; ring slot 48 KB, ring-3 = 144 KB -> 1 block/CU, 8 waves (same
// residency as the verified m201 template). Phase skeleton per m201:
//   { ds_read NEXT-phase frags || stage } ; s_barrier ; lgkmcnt(0) ;
//   sched_barrier ; setprio(1) 8xMFMA setprio(0) ; s_barrier
// Phase p computes nf=p from regs loaded in phase p-1 (cross-phase staging);
// phase 3 preloads next tile's xf (8xb128) + wf0. vmcnt(6) ONCE per iter at
// phase 2 (retires tile i+1 exactly; never 0 mid-loop).
#define KSX 1048576   // shorts: x advance per cc (4 ci-groups * 32768 * 8)
#define KSW 4096      // shorts: wn advance per cc
#define RB  24576     // shorts: ring slot (2x8192 x + 2x4096 w)
__global__ __launch_bounds__(512, 2) void conv_m2(
    const u16* __restrict__ wsb, const float* __restrict__ bias,
    float* __restrict__ out) {
    __shared__ __align__(16) u16 lds[3 * RB];     // 147456 B
    const u16* xt = wsb + 524288;
    const u16* wn = wsb + 512;
    const u16* zp = wsb;                          // zero page (memset)

    const int t = threadIdx.x, lane = t & 63, wid = t >> 6;
    const int ll = lane & 15, g = lane >> 4;
    const int mslice = wid >> 1, ncol = wid & 1;

    int wg = ((blockIdx.x & 7) << 7) | (blockIdx.x >> 3);   // XCD swizzle
    const int b = wg >> 7, dt = (wg >> 3) & 15, ht = wg & 7;
    const int d0 = dt * 2, h0 = ht * 4;

    // loop-invariant ds_read offsets (shorts, within ring slot)
    const int pos0 = mslice * 64 + ll;
    const int xro = pos0 * 32 + ((g ^ ((pos0 >> 1) & 3)) * 8);
    const int co0 = ncol * 64 + ll;
    const int wro = 16384 + co0 * 32 + ((g ^ ((co0 >> 1) & 3)) * 8);

    // staging lane constants (per cc: 2 x-gloads + 1 w-gload per thread)
    const int posA = wid * 32 + (lane >> 2);
    const int slot = lane & 3;
    const int pdA = posA >> 7, phA = (posA >> 5) & 3, wA = posA & 31;
    const int gA = slot ^ ((posA >> 1) & 3);
    const int wco = wid * 16 + (lane >> 2);
    const u16* wsrc = wn + wco * 32 + ((slot ^ ((wco >> 1) & 3)) * 8);

    f32x4 acc[4][4];
#pragma unroll
    for (int i = 0; i < 4; ++i)
#pragma unroll
        for (int j = 0; j < 4; ++j) acc[i][j] = (f32x4){0.f, 0.f, 0.f, 0.f};

    // staging cursor (cc-granular; tap addr recomputed at cc_s==0)
    int od_s = 0, oh_s = 0, ow_s = 0, cc_s = 0;
    const u16* xsA = xt; bool okA = false, okB = false;

    bf16x8 xa[4][2], xb[4][2];    // x frag banks (alternate per iter)
    bf16x8 wfA[2], wfB[2];        // w frag banks (roles fixed per phase)

#define DO_STAGE(SB, H) { \
    if (cc_s == 0) { \
        int Dx = d0 + pdA - 1 + od_s, Hx = h0 + phA - 1 + oh_s, Wx = wA - 1 + ow_s; \
        bool dh_ = ((unsigned)Dx < 32u) && ((unsigned)Hx < 32u); \
        okA = dh_ && ((unsigned)Wx < 32u); \
        okB = dh_ && (Wx < 16); \
        xsA = xt + (long)((b * 16 + gA) * 32768 + Dx * 1024 + Hx * 32 + Wx) * 8; } \
    gload_lds16(okA ? (const void*)xsA : (const void*)zp, \
                (void*)&lds[(SB)*RB + (H)*8192 + wid*1024]); \
    gload_lds16(okB ? (const void*)(xsA + 128) : (const void*)zp, \
                (void*)&lds[(SB)*RB + (H)*8192 + wid*1024 + 512]); \
    gload_lds16((const void*)wsrc, \
                (void*)&lds[(SB)*RB + 16384 + (H)*4096 + wid*512]); \
    xsA += KSX; wsrc += KSW; \
    if (++cc_s == 4) { cc_s = 0; \
        if (++ow_s == 3) { ow_s = 0; if (++oh_s == 3) { oh_s = 0; ++od_s; } } } }

#define MFMA8(P, WF, XC) { \
    __builtin_amdgcn_s_setprio(1); \
    _Pragma("unroll") for (int mf = 0; mf < 4; ++mf) { \
        acc[mf][P] = __builtin_amdgcn_mfma_f32_16x16x32_bf16(WF[0], XC[mf][0], acc[mf][P], 0, 0, 0); \
        acc[mf][P] = __builtin_amdgcn_mfma_f32_16x16x32_bf16(WF[1], XC[mf][1], acc[mf][P], 0, 0, 0); } \
    __builtin_amdgcn_s_setprio(0); }

// m201 order: barrier FIRST, then lgkmcnt(0) (read latency hides under the
// barrier wait), then sched_barrier so MFMAs can't hoist above the wait.
#define BARSYNC() { \
    asm volatile("s_barrier" ::: "memory"); \
    asm volatile("s_waitcnt lgkmcnt(0)" ::: "memory"); \
    __builtin_amdgcn_sched_barrier(0); }
#define TBAR() asm volatile("s_barrier" ::: "memory");

// Phase roles (invariant every iter): enter with wfA = nf0(C), XC = xf(C).
//  ph0: load nf1->wfB | stage cc0 | MFMA(nf0, wfA)
//  ph1: load nf2->wfA | stage cc1 | MFMA(nf1, wfB)
//  ph2: load nf3->wfB |           | MFMA(nf2, wfA) ; vmcnt(VM)
//  ph3: load xf(N)->XN, nf0(N)->wfA | MFMA(nf3, wfB)
#define ITER(C, N, S, XC, XN, DOST, VM, DONEXT) { \
    wfB[0] = *(const bf16x8*)&lds[(C)*RB + wro + 512]; \
    wfB[1] = *(const bf16x8*)&lds[(C)*RB + wro + 512 + 4096]; \
    if (DOST) DO_STAGE(S, 0); \
    BARSYNC(); MFMA8(0, wfA, XC); TBAR(); \
    wfA[0] = *(const bf16x8*)&lds[(C)*RB + wro + 1024]; \
    wfA[1] = *(const bf16x8*)&lds[(C)*RB + wro + 1024 + 4096]; \
    if (DOST) DO_STAGE(S, 1); \
    BARSYNC(); MFMA8(1, wfB, XC); TBAR(); \
    wfB[0] = *(const bf16x8*)&lds[(C)*RB + wro + 1536]; \
    wfB[1] = *(const bf16x8*)&lds[(C)*RB + wro + 1536 + 4096]; \
    BARSYNC(); MFMA8(2, wfA, XC); \
    asm volatile("s_waitcnt " VM ::: "memory"); TBAR(); \
    if (DONEXT) { \
        _Pragma("unroll") for (int mf = 0; mf < 4; ++mf) { \
            XN[mf][0] = *(const bf16x8*)&lds[(N)*RB + xro + mf * 512]; \
            XN[mf][1] = *(const bf16x8*)&lds[(N)*RB + xro + mf * 512 + 8192]; } \
        wfA[0] = *(const bf16x8*)&lds[(N)*RB + wro]; \
        wfA[1] = *(const bf16x8*)&lds[(N)*RB + wro + 4096]; } \
    BARSYNC(); MFMA8(3, wfB, XC); TBAR(); }

    // prologue: stage tiles 0,1 (12 loads); preload xa + wfA from tile 0
    DO_STAGE(0, 0); DO_STAGE(0, 1); DO_STAGE(1, 0); DO_STAGE(1, 1);
    asm volatile("s_waitcnt vmcnt(6)" ::: "memory");   // tile 0 landed (mine)
    asm volatile("s_barrier" ::: "memory");            // tile 0 landed (all)
#pragma unroll
    for (int mf = 0; mf < 4; ++mf) {
        xa[mf][0] = *(const bf16x8*)&lds[xro + mf * 512];
        xa[mf][1] = *(const bf16x8*)&lds[xro + mf * 512 + 8192];
    }
    wfA[0] = *(const bf16x8*)&lds[wro];
    wfA[1] = *(const bf16x8*)&lds[wro + 4096];
    asm volatile("s_waitcnt lgkmcnt(0)" ::: "memory");
    __builtin_amdgcn_sched_barrier(0);
    asm volatile("s_barrier" ::: "memory");

    for (int m = 0; m < 8; ++m) {       // iters 0..47
        ITER(0, 1, 2, xa, xb, 1, "vmcnt(6)", 1);
        ITER(1, 2, 0, xb, xa, 1, "vmcnt(6)", 1);
        ITER(2, 0, 1, xa, xb, 1, "vmcnt(6)", 1);
        ITER(0, 1, 2, xb, xa, 1, "vmcnt(6)", 1);
        ITER(1, 2, 0, xa, xb, 1, "vmcnt(6)", 1);
        ITER(2, 0, 1, xb, xa, 1, "vmcnt(6)", 1);
    }
    ITER(0, 1, 2, xa, xb, 1, "vmcnt(6)", 1);   // i=48
    ITER(1, 2, 0, xb, xa, 1, "vmcnt(6)", 1);   // i=49
    ITER(2, 0, 1, xa, xb, 1, "vmcnt(6)", 1);   // i=50
    ITER(0, 1, 2, xb, xa, 1, "vmcnt(6)", 1);   // i=51, stages tile53->slot2
    ITER(1, 2, 0, xa, xb, 0, "vmcnt(0)", 1);   // i=52
    ITER(2, 0, 1, xb, xa, 0, "vmcnt(0)", 0);   // i=53, no next-reads

    // epilogue: bias + leaky_relu + sqrt(2) + clamp, direct stores
    const int pd = mslice >> 1, phb = (mslice & 1) * 2;
#pragma unroll
    for (int nf = 0; nf < 4; ++nf) {
        f32x4 bb = *(const f32x4*)&bias[ncol * 64 + nf * 16 + g * 4];
#pragma unroll
        for (int mf = 0; mf < 4; ++mf) {
            const int wq = (mf & 1) * 16 + ll;
            const int hh = h0 + phb + (mf >> 1);
            float* orow = out + ((size_t)(b * 128 + ncol * 64 + nf * 16 + g * 4) << 15)
                          + (d0 + pd) * 1024 + hh * 32 + wq;
#pragma unroll
            for (int q = 0; q < 4; ++q) {
                float v = acc[mf][nf][q] + bb[q];
                v = v > 0.f ? v : v * 0.2f;
                v *= 1.41421356237f;
                v = fminf(fmaxf(v, -256.f), 256.f);
                orow[(size_t)q << 15] = v;
            }
        }
    }
#undef DO_STAGE
#undef MFMA8
#undef BARSYNC
#undef TBAR
#undef ITER
}

// ---------------- Fallback conv (R4, proven) if ws too small -----------------
#define NPOS 544
__global__ __launch_bounds__(256, 4) void conv_fb(
    const float* __restrict__ x, const u16* __restrict__ wn,
    const float* __restrict__ bias, float* __restrict__ out) {
    __shared__ __align__(16) u16 lds[NPOS * 32];
    float* ldsf = reinterpret_cast<float*>(lds);
    const int t = threadIdx.x;
    const int lane = t & 63;
    const int wid  = t >> 6;
    const int wr   = wid >> 1;
    const int wcn  = wid & 1;
    const int ll   = lane & 15;
    const int g    = lane >> 4;
    const int bid = blockIdx.x;
    const int b  = bid >> 8;
    const int dt = (bid >> 4) & 15, ht = bid & 15;
    const int d0 = dt * 2, h0 = ht * 2;
    const int sw  = t & 31;
    const int sg  = (t >> 5) & 3;
    const int rhi = t >> 7;
    f32x4 acc[4][4];
#pragma unroll
    for (int i = 0; i < 4; ++i)
#pragma unroll
        for (int j = 0; j < 4; ++j) acc[i][j] = (f32x4){0.f, 0.f, 0.f, 0.f};
    float bv[4][4];
#pragma unroll
    for (int nf = 0; nf < 4; ++nf) {
        f32x4 bb = *(const f32x4*)&bias[wcn * 64 + nf * 16 + g * 4];
#pragma unroll
        for (int q = 0; q < 4; ++q) bv[nf][q] = bb[q];
    }
    if (t < 128) {
        int pi  = t >> 2;
        int row = pi >> 1;
        int pos = row * 34 + (pi & 1) * 33;
        bf16x8 z = {0, 0, 0, 0, 0, 0, 0, 0};
        *(bf16x8*)&lds[pos * 32 + (t & 3) * 8] = z;
    }
    for (int c = 0; c < 4; ++c) {
        if (c) __syncthreads();
#pragma unroll
        for (int p = 0; p < 8; ++p) {
            int rowid = p * 2 + rhi;
            int pd = rowid >> 2, ph = rowid & 3;
            int d = d0 - 1 + pd, h = h0 - 1 + ph;
            bool ok = ((unsigned)d < 32u) && ((unsigned)h < 32u);
            const float* src = x + (((b * 128 + c * 32 + sg * 8) * 32 + d) * 32 + h) * 32 + sw;
            float v[8];
#pragma unroll
            for (int j = 0; j < 8; ++j) v[j] = ok ? src[j * 32768] : 0.f;
            bf16x8 pk;
#pragma unroll
            for (int j = 0; j < 8; ++j) pk[j] = (short)f2bf(v[j]);
            int pos = rowid * 34 + sw + 1;
            int sl = sg ^ ((pos >> 1) & 3);
            *(bf16x8*)&lds[pos * 32 + sl * 8] = pk;
        }
        __syncthreads();
        const u16* wbase = wn + c * 4096 + ((wcn * 64 + ll) * 32 + g * 8);
        bf16x8 wf[4];
#pragma unroll
        for (int nf = 0; nf < 4; ++nf) wf[nf] = *(const bf16x8*)&wbase[nf * 512];
#pragma unroll
        for (int tap = 0; tap < 27; ++tap) {
            const int od = tap / 9, oh = (tap / 3) % 3, ow = tap % 3;
            bf16x8 wfn[4];
            if (tap < 26) {
#pragma unroll
                for (int nf = 0; nf < 4; ++nf)
                    wfn[nf] = *(const bf16x8*)&wbase[(tap + 1) * 16384 + nf * 512];
            }
            bf16x8 xf[4];
#pragma unroll
            for (int mf = 0; mf < 4; ++mf) {
                int pos = ((wr + od) * 4 + (mf >> 1) + oh) * 34 + (mf & 1) * 16 + ll + ow;
                int sl = g ^ ((pos >> 1) & 3);
                xf[mf] = *(const bf16x8*)&lds[pos * 32 + sl * 8];
            }
            __builtin_amdgcn_s_setprio(1);
#pragma unroll
            for (int mf = 0; mf < 4; ++mf)
#pragma unroll
                for (int nf = 0; nf < 4; ++nf)
                    acc[mf][nf] = __builtin_amdgcn_mfma_f32_16x16x32_bf16(
                        wf[nf], xf[mf], acc[mf][nf], 0, 0, 0);
            __builtin_amdgcn_s_setprio(0);
            if (tap < 26) {
#pragma unroll
                for (int nf = 0; nf < 4; ++nf) wf[nf] = wfn[nf];
            }
        }
    }
#pragma unroll
    for (int p = 0; p < 4; ++p) {
        const int dd = p >> 1, hh = p & 1;
        __syncthreads();
        if (wr == dd) {
#pragma unroll
            for (int whalf = 0; whalf < 2; ++whalf) {
                const int mf = hh * 2 + whalf;
#pragma unroll
                for (int nf = 0; nf < 4; ++nf) {
#pragma unroll
                    for (int q = 0; q < 4; ++q) {
                        const int co = wcn * 64 + nf * 16 + g * 4 + q;
                        float v = acc[mf][nf][q] + bv[nf][q];
                        v = v > 0.f ? v : v * 0.2f;
                        v *= 1.41421356237f;
                        v = fminf(fmaxf(v, -256.f), 256.f);
                        ldsf[co * 33 + whalf * 16 + ll] = v;
                    }
                }
            }
        }
        __syncthreads();
#pragma unroll
        for (int it = 0; it < 4; ++it) {
            const int row = it * 32 + (t >> 3);
            const int ls  = t & 7;
            f32x4 v = *(f32x4*)&ldsf[row * 33 + ls * 4];
            *(f32x4*)&out[(size_t)(b * 128 + row) * 32768 +
                          (d0 + dd) * 1024 + (h0 + hh) * 32 + ls * 4] = v;
        }
    }
}

extern "C" void kernel_launch(void* const* d_in, const int* in_sizes, int n_in,
                              void* d_out, int out_size, void* d_ws, size_t ws_size,
                              hipStream_t stream) {
    const float* x    = (const float*)d_in[0];
    const float* w    = (const float*)d_in[1];
    const float* bias = (const float*)d_in[2];
    float* out        = (float*)d_out;
    u16* wsb          = (u16*)d_ws;

    hipMemsetAsync(d_ws, 0, 1024, stream);                 // zero page
    prep_w_k<<<128, 256, 0, stream>>>(w, wsb + 512);       // wn at +1KB

    if (ws_size >= 68157440ull) {
        xpose_k<<<8192, 256, 0, stream>>>(x, wsb + 524288);  // xt at +1MB
        conv_m2<<<1024, 512, 0, stream>>>(wsb, bias, out);
    } else {
        conv_fb<<<2048, 256, 0, stream>>>(x, wsb + 512, bias, out);
    }
}

// Round 18
// 290.763 us; speedup vs baseline: 1.0463x; 1.0463x over previous
//
#include <hip/hip_runtime.h>

typedef short bf16x8 __attribute__((ext_vector_type(8)));
typedef float f32x4  __attribute__((ext_vector_type(4)));
typedef unsigned short u16;

static __device__ __forceinline__ u16 f2bf(float f) {
    unsigned int u = __builtin_bit_cast(unsigned int, f);
    u += 0x7FFFu + ((u >> 16) & 1u);   // round-to-nearest-even
    return (u16)(u >> 16);
}

static __device__ __forceinline__ void gload_lds16(const void* g, void* l) {
    __builtin_amdgcn_global_load_lds((const __attribute__((address_space(1))) void*)g,
                                     (__attribute__((address_space(3))) void*)l, 16, 0, 0);
}

// ---------------- Kernel 1: demodulate + convert weights to bf16 -------------
// wn[((tap*4 + cc)*128 + co)*32 + ci_in_chunk]  == kstep-major [k108][co128][ci32]
__global__ __launch_bounds__(256) void prep_w_k(const float* __restrict__ w,
                                                u16* __restrict__ wn) {
    const int co = blockIdx.x;
    const int t  = threadIdx.x;
    const float* wc = w + co * 3456;
    float s = 0.f;
    for (int i = t; i < 3456; i += 256) { float v = wc[i]; s += v * v; }
#pragma unroll
    for (int off = 32; off; off >>= 1) s += __shfl_down(s, off);
    __shared__ float red[4];
    __shared__ float dsh;
    if ((t & 63) == 0) red[t >> 6] = s;
    __syncthreads();
    if (t == 0) dsh = rsqrtf(red[0] + red[1] + red[2] + red[3] + 1e-8f);
    __syncthreads();
    const float d = dsh;
    for (int i = t; i < 3456; i += 256) {
        int ci = i / 27, tap = i - ci * 27;
        float v = wc[i] * d;
        wn[((tap * 4 + (ci >> 5)) * 128 + co) * 32 + (ci & 31)] = f2bf(v);
    }
}

// ---------------- Kernel 2: transpose x -> channels-grouped bf16 -------------
// xt[((b*16 + g)*32768 + d*1024 + h*32 + w)*8 + j] = bf16(x[b][g*8+j][d][h][w])
__global__ __launch_bounds__(256) void xpose_k(const float* __restrict__ x,
                                               u16* __restrict__ xt) {
    const int bid = blockIdx.x;
    const int b = bid >> 10, d = (bid >> 5) & 31, h = bid & 31;
    const int t = threadIdx.x;
    const int w = t & 31, cg = t >> 5;
    const int base_dhw = d * 1024 + h * 32 + w;
#pragma unroll
    for (int r = 0; r < 2; ++r) {
        int g = cg + r * 8;
        const float* src = x + ((size_t)(b * 128 + g * 8) << 15) + base_dhw;
        bf16x8 pk;
#pragma unroll
        for (int j = 0; j < 8; ++j) pk[j] = (short)f2bf(src[(size_t)j << 15]);
        *(bf16x8*)&xt[((size_t)((b * 16 + g) << 15) + base_dhw) * 8] = pk;
    }
}

// ---------------- Kernel 3: conv3d — 128x64 wave tile, ring-3 (session best) -
// 256 thr = 4 waves (2 mslice x 2 ncol). Tile M=256 (d2,h4,w32), N=128.
// Wave tile 128x64: acc 8x4 f32x4 = 128 (AGPR); frags single-buffered.
// LDS ring: 3 x (x 16KB + w 8KB) = 72 KB -> 2 phase-staggered blocks/CU.
// Step k: frag ds_reads (slot k%3) -> STAGE st(k+2) -> 32 MFMA ->
// lgkmcnt(0); vmcnt(6); s_barrier. Measured: 268 us conv, MfmaUtil 39%,
// 866 TF-class wall — best of 8 structurally distinct schedules (R5..R16).
#define KSX 1048576   // shorts: x advance per k-step (4 ci-groups * 32768 * 8)
#define KSW 4096      // shorts: wn advance per k-step
#define RB  12288     // shorts: ring stride (8192 x + 4096 w)
__global__ __launch_bounds__(256, 2) void conv_wx(
    const u16* __restrict__ wsb, const float* __restrict__ bias,
    float* __restrict__ out) {
    __shared__ __align__(16) u16 lds[3 * RB];     // 73728 B
    const u16* xt = wsb + 524288;
    const u16* wn = wsb + 512;
    const u16* zp = wsb;                          // zero page (memset)

    const int t = threadIdx.x, lane = t & 63, wid = t >> 6;
    const int ll = lane & 15, g = lane >> 4;
    const int mslice = wid >> 1, ncol = wid & 1;

    int wg = ((blockIdx.x & 7) << 7) | (blockIdx.x >> 3);   // XCD swizzle
    const int b = wg >> 7, dt = (wg >> 3) & 15, ht = wg & 7;
    const int d0 = dt * 2, h0 = ht * 4;

    // loop-invariant ds_read offsets (shorts, within ring slot)
    const int pos0 = mslice * 128 + ll;
    const int xro = pos0 * 32 + ((g ^ ((pos0 >> 1) & 3)) * 8);
    const int co0 = ncol * 64 + ll;
    const int wro = 8192 + co0 * 32 + ((g ^ ((co0 >> 1) & 3)) * 8);

    // staging lane constants: x = 4 gloads (rows wid*2, wid*2+1; w-halves),
    // w = 2 gloads. All dsts linear: base + lane*8 shorts.
    const int lhi = lane >> 2, slot = lane & 3;
    const int posA = wid * 64 + lhi;
    const int gA = slot ^ ((posA >> 1) & 3);
    const int phr = (wid * 2) & 3;
    const int pdr = wid >> 1;
    const u16* wsrc = wn + (wid * 32 + lhi) * 32 +
                      ((slot ^ (((wid * 32 + lhi) >> 1) & 3)) * 8);

    f32x4 acc[8][4];
#pragma unroll
    for (int i = 0; i < 8; ++i)
#pragma unroll
        for (int j = 0; j < 4; ++j) acc[i][j] = (f32x4){0.f, 0.f, 0.f, 0.f};

    // staging cursor (tracks staged step s; recompute base at s%4==0)
    int od_s = 0, oh_s = 0, ow_s = 0, cc_s = 0;
    const u16* xsA = xt; bool okA = false, okB = false, rok0 = false, rok1 = false;

#define DO_STAGE(SB) { \
    if (cc_s == 0) { \
        int Dx  = d0 + pdr - 1 + od_s; \
        int Hx0 = h0 + phr - 1 + oh_s; \
        int Wx  = lhi - 1 + ow_s; \
        bool dok = ((unsigned)Dx < 32u); \
        rok0 = dok && ((unsigned)Hx0 < 32u); \
        rok1 = dok && ((unsigned)(Hx0 + 1) < 32u); \
        okA = ((unsigned)Wx < 32u); \
        okB = (Wx < 16); \
        xsA = xt + (long)((b * 16 + gA) * 32768 + Dx * 1024 + Hx0 * 32 + Wx) * 8; } \
    gload_lds16((rok0 && okA) ? (const void*)xsA          : (const void*)zp, (void*)&lds[(SB)*RB + wid*2048]); \
    gload_lds16((rok0 && okB) ? (const void*)(xsA + 128)  : (const void*)zp, (void*)&lds[(SB)*RB + wid*2048 + 512]); \
    gload_lds16((rok1 && okA) ? (const void*)(xsA + 256)  : (const void*)zp, (void*)&lds[(SB)*RB + wid*2048 + 1024]); \
    gload_lds16((rok1 && okB) ? (const void*)(xsA + 384)  : (const void*)zp, (void*)&lds[(SB)*RB + wid*2048 + 1536]); \
    gload_lds16((const void*)wsrc,         (void*)&lds[(SB)*RB + 8192 + wid*1024]); \
    gload_lds16((const void*)(wsrc + 512), (void*)&lds[(SB)*RB + 8192 + wid*1024 + 512]); \
    xsA += KSX; wsrc += KSW; \
    if (++cc_s == 4) { cc_s = 0; \
        if (++ow_s == 3) { ow_s = 0; if (++oh_s == 3) { oh_s = 0; ++od_s; } } } }

#define KSTEP(RD, SB, DOST, VMSTR, DOBAR) { \
    bf16x8 xf[8], wf[4]; \
    _Pragma("unroll") for (int mf = 0; mf < 8; ++mf) \
        xf[mf] = *(const bf16x8*)&lds[(RD)*RB + xro + mf * 512]; \
    _Pragma("unroll") for (int nf = 0; nf < 4; ++nf) \
        wf[nf] = *(const bf16x8*)&lds[(RD)*RB + wro + nf * 512]; \
    if (DOST) DO_STAGE(SB); \
    __builtin_amdgcn_s_setprio(1); \
    _Pragma("unroll") for (int mf = 0; mf < 8; ++mf) \
    _Pragma("unroll") for (int nf = 0; nf < 4; ++nf) \
        acc[mf][nf] = __builtin_amdgcn_mfma_f32_16x16x32_bf16(wf[nf], xf[mf], acc[mf][nf], 0, 0, 0); \
    __builtin_amdgcn_s_setprio(0); \
    if (DOBAR) { \
        asm volatile("s_waitcnt lgkmcnt(0)" ::: "memory"); \
        asm volatile("s_waitcnt " VMSTR ::: "memory"); \
        asm volatile("s_barrier" ::: "memory"); } }

    // prologue: stage st(0)->slot0, st(1)->slot1 (12 loads in flight)
    DO_STAGE(0); DO_STAGE(1);
    asm volatile("s_waitcnt vmcnt(6)" ::: "memory");  // st(0) landed (mine)
    asm volatile("s_barrier" ::: "memory");           // st(0) landed (all)

    for (int m = 0; m < 35; ++m) {      // k = 0..104
        KSTEP(0, 2, 1, "vmcnt(6)", 1);
        KSTEP(1, 0, 1, "vmcnt(6)", 1);
        KSTEP(2, 1, 1, "vmcnt(6)", 1);
    }
    KSTEP(0, 2, 1, "vmcnt(6)", 1);      // k=105, stages st(107)->slot2
    KSTEP(1, 0, 0, "vmcnt(0)", 1);      // k=106, drain st(107)
    KSTEP(2, 0, 0, "vmcnt(0)", 0);      // k=107, no trailing sync

    // epilogue: bias + leaky_relu + sqrt(2) + clamp, direct stores
    const int dd = d0 + mslice;
#pragma unroll
    for (int nf = 0; nf < 4; ++nf) {
        f32x4 bb = *(const f32x4*)&bias[ncol * 64 + nf * 16 + g * 4];
#pragma unroll
        for (int mf = 0; mf < 8; ++mf) {
            const int wq = (mf & 1) * 16 + ll;
            const int hh = h0 + (mf >> 1);
            float* orow = out + ((size_t)(b * 128 + ncol * 64 + nf * 16 + g * 4) << 15)
                          + dd * 1024 + hh * 32 + wq;
#pragma unroll
            for (int q = 0; q < 4; ++q) {
                float v = acc[mf][nf][q] + bb[q];
                v = v > 0.f ? v : v * 0.2f;
                v *= 1.41421356237f;
                v = fminf(fmaxf(v, -256.f), 256.f);
                orow[(size_t)q << 15] = v;
            }
        }
    }
#undef DO_STAGE
#undef KSTEP
}

// ---------------- Fallback conv (R4, proven) if ws too small -----------------
#define NPOS 544
__global__ __launch_bounds__(256, 4) void conv_fb(
    const float* __restrict__ x, const u16* __restrict__ wn,
    const float* __restrict__ bias, float* __restrict__ out) {
    __shared__ __align__(16) u16 lds[NPOS * 32];
    float* ldsf = reinterpret_cast<float*>(lds);
    const int t = threadIdx.x;
    const int lane = t & 63;
    const int wid  = t >> 6;
    const int wr   = wid >> 1;
    const int wcn  = wid & 1;
    const int ll   = lane & 15;
    const int g    = lane >> 4;
    const int bid = blockIdx.x;
    const int b  = bid >> 8;
    const int dt = (bid >> 4) & 15, ht = bid & 15;
    const int d0 = dt * 2, h0 = ht * 2;
    const int sw  = t & 31;
    const int sg  = (t >> 5) & 3;
    const int rhi = t >> 7;
    f32x4 acc[4][4];
#pragma unroll
    for (int i = 0; i < 4; ++i)
#pragma unroll
        for (int j = 0; j < 4; ++j) acc[i][j] = (f32x4){0.f, 0.f, 0.f, 0.f};
    float bv[4][4];
#pragma unroll
    for (int nf = 0; nf < 4; ++nf) {
        f32x4 bb = *(const f32x4*)&bias[wcn * 64 + nf * 16 + g * 4];
#pragma unroll
        for (int q = 0; q < 4; ++q) bv[nf][q] = bb[q];
    }
    if (t < 128) {
        int pi  = t >> 2;
        int row = pi >> 1;
        int pos = row * 34 + (pi & 1) * 33;
        bf16x8 z = {0, 0, 0, 0, 0, 0, 0, 0};
        *(bf16x8*)&lds[pos * 32 + (t & 3) * 8] = z;
    }
    for (int c = 0; c < 4; ++c) {
        if (c) __syncthreads();
#pragma unroll
        for (int p = 0; p < 8; ++p) {
            int rowid = p * 2 + rhi;
            int pd = rowid >> 2, ph = rowid & 3;
            int d = d0 - 1 + pd, h = h0 - 1 + ph;
            bool ok = ((unsigned)d < 32u) && ((unsigned)h < 32u);
            const float* src = x + (((b * 128 + c * 32 + sg * 8) * 32 + d) * 32 + h) * 32 + sw;
            float v[8];
#pragma unroll
            for (int j = 0; j < 8; ++j) v[j] = ok ? src[j * 32768] : 0.f;
            bf16x8 pk;
#pragma unroll
            for (int j = 0; j < 8; ++j) pk[j] = (short)f2bf(v[j]);
            int pos = rowid * 34 + sw + 1;
            int sl = sg ^ ((pos >> 1) & 3);
            *(bf16x8*)&lds[pos * 32 + sl * 8] = pk;
        }
        __syncthreads();
        const u16* wbase = wn + c * 4096 + ((wcn * 64 + ll) * 32 + g * 8);
        bf16x8 wf[4];
#pragma unroll
        for (int nf = 0; nf < 4; ++nf) wf[nf] = *(const bf16x8*)&wbase[nf * 512];
#pragma unroll
        for (int tap = 0; tap < 27; ++tap) {
            const int od = tap / 9, oh = (tap / 3) % 3, ow = tap % 3;
            bf16x8 wfn[4];
            if (tap < 26) {
#pragma unroll
                for (int nf = 0; nf < 4; ++nf)
                    wfn[nf] = *(const bf16x8*)&wbase[(tap + 1) * 16384 + nf * 512];
            }
            bf16x8 xf[4];
#pragma unroll
            for (int mf = 0; mf < 4; ++mf) {
                int pos = ((wr + od) * 4 + (mf >> 1) + oh) * 34 + (mf & 1) * 16 + ll + ow;
                int sl = g ^ ((pos >> 1) & 3);
                xf[mf] = *(const bf16x8*)&lds[pos * 32 + sl * 8];
            }
            __builtin_amdgcn_s_setprio(1);
#pragma unroll
            for (int mf = 0; mf < 4; ++mf)
#pragma unroll
                for (int nf = 0; nf < 4; ++nf)
                    acc[mf][nf] = __builtin_amdgcn_mfma_f32_16x16x32_bf16(
                        wf[nf], xf[mf], acc[mf][nf], 0, 0, 0);
            __builtin_amdgcn_s_setprio(0);
            if (tap < 26) {
#pragma unroll
                for (int nf = 0; nf < 4; ++nf) wf[nf] = wfn[nf];
            }
        }
    }
#pragma unroll
    for (int p = 0; p < 4; ++p) {
        const int dd = p >> 1, hh = p & 1;
        __syncthreads();
        if (wr == dd) {
#pragma unroll
            for (int whalf = 0; whalf < 2; ++whalf) {
                const int mf = hh * 2 + whalf;
#pragma unroll
                for (int nf = 0; nf < 4; ++nf) {
#pragma unroll
                    for (int q = 0; q < 4; ++q) {
                        const int co = wcn * 64 + nf * 16 + g * 4 + q;
                        float v = acc[mf][nf][q] + bv[nf][q];
                        v = v > 0.f ? v : v * 0.2f;
                        v *= 1.41421356237f;
                        v = fminf(fmaxf(v, -256.f), 256.f);
                        ldsf[co * 33 + whalf * 16 + ll] = v;
                    }
                }
            }
        }
        __syncthreads();
#pragma unroll
        for (int it = 0; it < 4; ++it) {
            const int row = it * 32 + (t >> 3);
            const int ls  = t & 7;
            f32x4 v = *(f32x4*)&ldsf[row * 33 + ls * 4];
            *(f32x4*)&out[(size_t)(b * 128 + row) * 32768 +
                          (d0 + dd) * 1024 + (h0 + hh) * 32 + ls * 4] = v;
        }
    }
}

extern "C" void kernel_launch(void* const* d_in, const int* in_sizes, int n_in,
                              void* d_out, int out_size, void* d_ws, size_t ws_size,
                              hipStream_t stream) {
    const float* x    = (const float*)d_in[0];
    const float* w    = (const float*)d_in[1];
    const float* bias = (const float*)d_in[2];
    float* out        = (float*)d_out;
    u16* wsb          = (u16*)d_ws;

    hipMemsetAsync(d_ws, 0, 1024, stream);                 // zero page
    prep_w_k<<<128, 256, 0, stream>>>(w, wsb + 512);       // wn at +1KB

    if (ws_size >= 68157440ull) {
        xpose_k<<<8192, 256, 0, stream>>>(x, wsb + 524288);  // xt at +1MB
        conv_wx<<<1024, 256, 0, stream>>>(wsb, bias, out);
    } else {
        conv_fb<<<2048, 256, 0, stream>>>(x, wsb + 512, bias, out);
    }
}